// Round 16
// baseline (168.569 us; speedup 1.0000x reference)
//
#include <hip/hip_runtime.h>

// Flash attention forward, fp32 in/out, fp16 MFMA compute.
// B=8, SQ=SK=4096, D=64. scores = (Q/x5) K^T ; softmax ; O = P V.
// R38 = R36 with the K/V LDS ROUND-TRIP DELETED: fragments load directly
// global->register from the prepass-swizzled Kh/Vt (each lane's fragment is
// a contiguous 16B at a computable global address - that's what the prepass
// layout was designed for). Deletes: staging DMA, loop ds_reads, 2.29M
// bank-conflict cycles, AND the per-kt __syncthreads (no shared loop state;
// each wave independent; compiler tracks its own counted vmcnt per load -
// the R32 race class cannot exist). Software pipeline in plain C++:
// kf(t+1) issued after QK(t) (hides under softmax+PV); vf(t+1) issued after
// PV(t) (hides under next QK+softmax). Cost: mh-pair redundant L2 traffic
// (~8 TB/s aggregate vs 34.5 L2 ceiling). launch_bounds(512,1): grid 256 =
// exactly 1 block/CU, so the old (512,2) 128-VGPR cap bought NOTHING -
// free the register budget for the reg-resident pipeline (~240 peak).
// LDS shrinks to the 76KB epilogue overlay; ONE barrier in the kernel.
// Kept: fused intra-block split-K (8 waves: ks=w&3, mh=w>>2), in-LDS
// combine epilogue, 32x32x16 swapped QK^T, in-register softmax (max3 tree),
// permlane P redistribution, fused-l ones-MFMA, setprio, defer-max 11.5,
// XCD-affine b=flat&7, 2-launch scheme. zacc dropped (16 regs > 64 movs).

typedef _Float16 f16x8 __attribute__((ext_vector_type(8)));
typedef _Float16 f16x4 __attribute__((ext_vector_type(4)));
typedef __fp16   h16x2 __attribute__((ext_vector_type(2)));
typedef float    f32x4 __attribute__((ext_vector_type(4)));
typedef float    f32x16 __attribute__((ext_vector_type(16)));

constexpr int kB  = 8;
constexpr int kSQ = 4096;
constexpr int kSK = 4096;
constexpr int kD  = 64;
constexpr int KSPLIT = 4;
constexpr int SKH = kSK / KSPLIT;     // 1024 keys per split
constexpr int BQ  = 128;              // per block: 2 mhalf x 2 M-tiles x 32 q
constexpr int MT  = 2;
constexpr int BK  = 64;
constexpr int PSTR = 72;              // LDS partial row stride (f16)
constexpr float kLog2e = 1.44269504088896340736f;
constexpr float kDeferThr = 11.5f;    // exp2-domain (~8 nats); P <= 2^11.5

static __device__ __forceinline__ f16x4 pack4(float a, float b, float c, float d) {
    h16x2 p0 = __builtin_amdgcn_cvt_pkrtz(a, b);
    h16x2 p1 = __builtin_amdgcn_cvt_pkrtz(c, d);
    f16x4 r;
    r[0] = (_Float16)p0[0]; r[1] = (_Float16)p0[1];
    r[2] = (_Float16)p1[0]; r[3] = (_Float16)p1[1];
    return r;
}
static __device__ __forceinline__ f16x8 pack8(const float4& a, const float4& c) {
    f16x4 lo = pack4(a.x, a.y, a.z, a.w);
    f16x4 hi = pack4(c.x, c.y, c.z, c.w);
    f16x8 f;
    f[0] = lo[0]; f[1] = lo[1]; f[2] = lo[2]; f[3] = lo[3];
    f[4] = hi[0]; f[5] = hi[1]; f[6] = hi[2]; f[7] = hi[3];
    return f;
}
static __device__ __forceinline__ unsigned pkrtz_u(float a, float b) {
    union { h16x2 h; unsigned u; } cv;
    cv.h = __builtin_amdgcn_cvt_pkrtz(a, b);
    return cv.u;
}
static __device__ __forceinline__ float xhalf_max(float x) {
    union { float f; unsigned u; } uv; uv.f = x;
    auto pr = __builtin_amdgcn_permlane32_swap(uv.u, uv.u, false, false);
    union { unsigned u; float f; } r0, r1;
    r0.u = pr[0]; r1.u = pr[1];
    return fmaxf(r0.f, r1.f);
}
static __device__ __forceinline__ float max3f(float a, float b, float c) {
    return fmaxf(fmaxf(a, b), c);   // clang fuses to v_max3_f32
}

// P slice (8 regs of one 32-key C-block) -> f16x8 PV fragment.
#define PA_SLICE(dst, sv, rb) do {                                          \
    unsigned c0 = pkrtz_u((sv)[(rb)+0], (sv)[(rb)+1]);                      \
    unsigned c1 = pkrtz_u((sv)[(rb)+2], (sv)[(rb)+3]);                      \
    unsigned c2 = pkrtz_u((sv)[(rb)+4], (sv)[(rb)+5]);                      \
    unsigned c3 = pkrtz_u((sv)[(rb)+6], (sv)[(rb)+7]);                      \
    auto r02 = __builtin_amdgcn_permlane32_swap(c0, c2, false, false);      \
    auto r13 = __builtin_amdgcn_permlane32_swap(c1, c3, false, false);      \
    union { unsigned u[4]; f16x8 v; } _r;                                   \
    _r.u[0] = r02[0]; _r.u[1] = r13[0]; _r.u[2] = r02[1]; _r.u[3] = r13[1]; \
    dst = _r.v;                                                             \
} while (0)

// ---------------- pre-pass: K -> Kh (swizzled fp16), V -> Vt (transposed,
// tiled, swizzled fp16). Kh[b][k][blk fb^(k&7)][8]; Vt[b][kt][f][blk kb^(f&7)][8].
__global__ __launch_bounds__(256, 2)
void fattn_prepass(const float* __restrict__ Kg,
                   const float* __restrict__ Vg,
                   _Float16* __restrict__ Kh,
                   _Float16* __restrict__ Vt)
{
    __shared__ _Float16 tr[kD][BK];

    const int tid = threadIdx.x;
    const int kt  = blockIdx.x;
    const int b   = blockIdx.y;

    const int k = tid >> 2;
    const int p = tid & 3;
    const int gk = kt * BK + k;

    {
        const float* src = Kg + ((size_t)b * kSK + gk) * kD + p * 16;
        const float4 a0 = *(const float4*)(src + 0);
        const float4 a1 = *(const float4*)(src + 4);
        const float4 a2 = *(const float4*)(src + 8);
        const float4 a3 = *(const float4*)(src + 12);
        _Float16* dst = Kh + ((size_t)b * kSK + gk) * kD;
        const int fb0 = 2 * p, fb1 = 2 * p + 1;
        *(f16x8*)&dst[(fb0 ^ (gk & 7)) * 8] = pack8(a0, a1);
        *(f16x8*)&dst[(fb1 ^ (gk & 7)) * 8] = pack8(a2, a3);
    }
    {
        const float* src = Vg + ((size_t)b * kSK + gk) * kD + p * 16;
        const float4 a0 = *(const float4*)(src + 0);
        const float4 a1 = *(const float4*)(src + 4);
        const float4 a2 = *(const float4*)(src + 8);
        const float4 a3 = *(const float4*)(src + 12);
        const float v[16] = {a0.x,a0.y,a0.z,a0.w, a1.x,a1.y,a1.z,a1.w,
                             a2.x,a2.y,a2.z,a2.w, a3.x,a3.y,a3.z,a3.w};
#pragma unroll
        for (int j = 0; j < 16; ++j)
            tr[p * 16 + j][k] = (_Float16)v[j];
    }
    __syncthreads();
    {
        const int f  = tid >> 2;
        const int p2 = tid & 3;
        const f16x8 b0 = *(const f16x8*)&tr[f][p2 * 16 + 0];
        const f16x8 b1 = *(const f16x8*)&tr[f][p2 * 16 + 8];
        _Float16* dst = Vt + (((size_t)b * 64 + kt) * kD + f) * BK;
        const int kb0 = 2 * p2, kb1 = 2 * p2 + 1;
        *(f16x8*)&dst[(kb0 ^ (f & 7)) * 8] = b0;
        *(f16x8*)&dst[(kb1 ^ (f & 7)) * 8] = b1;
    }
}

// ---------------- fused kernel: reg-direct K/V, barrier-free loop ----------------
__global__ __launch_bounds__(512, 1)
void fattn_fused(const float* __restrict__ Qg,
                 const _Float16* __restrict__ Kh,
                 const _Float16* __restrict__ Vt,
                 const float* __restrict__ sdiv,
                 float* __restrict__ Og)
{
    // LDS only for the split-K combine epilogue: 72KB + 4KB
    __shared__ __align__(16) _Float16 sPart[8][64][PSTR];
    __shared__ float2 sMl[8][64];

    const int tid  = threadIdx.x;
    const int w    = tid >> 6;      // 0..7
    const int lane = tid & 63;
    const int l31  = lane & 31;
    const int hi   = lane >> 5;
    const int ks   = w & 3;         // split
    const int mh   = w >> 2;        // q-half (0/1)

    // XCD-affine decode: b = flat&7 -> all 32 blocks of a batch on one XCD.
    const int flat = blockIdx.x;
    const int b    = flat & 7;
    const int qi   = flat >> 3;
    const int qb   = qi * BQ;

    const float qscale = kLog2e / sdiv[0];   // exp2 domain

    const float* Qb = Qg + ((size_t)b * kSQ + qb) * kD;
    const _Float16* Khb = Kh + ((size_t)b * kSK + (size_t)ks * SKH) * kD;
    const _Float16* Vtb = Vt + (((size_t)b * 64 + (size_t)ks * (SKH / BK)) * kD) * BK;

    // ---- Q fragments: q = qb + mh*64 + mt*32 + l31 ----
    f16x8 qf[MT][4];
#pragma unroll
    for (int mt = 0; mt < MT; ++mt) {
        const float* qrow = Qb + (size_t)(mh * 64 + mt * 32 + l31) * kD;
#pragma unroll
        for (int ds = 0; ds < 4; ++ds) {
            const float4 a  = *(const float4*)(qrow + ds * 16 + hi * 8);
            const float4 cc = *(const float4*)(qrow + ds * 16 + hi * 8 + 4);
            float4 as = make_float4(a.x * qscale, a.y * qscale, a.z * qscale, a.w * qscale);
            float4 cs = make_float4(cc.x * qscale, cc.y * qscale, cc.z * qscale, cc.w * qscale);
            qf[mt][ds] = pack8(as, cs);
        }
    }

    // ones A-fragment for the fused-l MFMA
    f16x8 ones;
#pragma unroll
    for (int j = 0; j < 8; ++j) ones[j] = (_Float16)1.0f;

    // Swizzled fragment offsets (f16 elements): each lane's fragment is a
    // contiguous 16B in the prepass layout -> direct global vector loads.
    int offA[4];
#pragma unroll
    for (int i = 0; i < 4; ++i)
        offA[i] = l31 * 64 + (((2 * i + hi) ^ (l31 & 7)) * 8);

    f32x16 oL[MT], oH[MT];
    f32x16 ol[MT];
    float m_i[MT];
#pragma unroll
    for (int mt = 0; mt < MT; ++mt) {
        m_i[mt] = -1e30f;
#pragma unroll
        for (int r = 0; r < 16; ++r) { oL[mt][r] = 0.0f; oH[mt][r] = 0.0f; ol[mt][r] = 0.0f; }
    }

    // ---- prologue: load tile-0 fragments (compiler tracks vmcnt) ----
    f16x8 kf0[4], kf1[4], vf0[4], vf1[4];
#pragma unroll
    for (int ds = 0; ds < 4; ++ds) {
        kf0[ds] = *(const f16x8*)&Khb[offA[ds]];
        kf1[ds] = *(const f16x8*)&Khb[offA[ds] + 2048];
    }
#pragma unroll
    for (int s = 0; s < 4; ++s) {
        vf0[s] = *(const f16x8*)&Vtb[offA[s]];
        vf1[s] = *(const f16x8*)&Vtb[offA[s] + 2048];
    }

    const int nIter = SKH / BK;   // 16
    for (int kt = 0; kt < nIter; ++kt) {
        const bool more = (kt + 1 < nIter);
        const _Float16* KhN = Khb + (size_t)(kt + 1) * (BK * kD);
        const _Float16* VtN = Vtb + (size_t)(kt + 1) * (kD * BK);

        // ---- QK phase (compiler waits kf's vmcnt before first MFMA) ----
        f32x16 s0[MT], s1[MT];
#pragma unroll
        for (int mt = 0; mt < MT; ++mt)
#pragma unroll
            for (int r = 0; r < 16; ++r) { s0[mt][r] = 0.0f; s1[mt][r] = 0.0f; }

        __builtin_amdgcn_s_setprio(1);
#pragma unroll
        for (int ds = 0; ds < 4; ++ds)
#pragma unroll
            for (int mt = 0; mt < MT; ++mt) {
                s0[mt] = __builtin_amdgcn_mfma_f32_32x32x16_f16(kf0[ds], qf[mt][ds], s0[mt], 0, 0, 0);
                s1[mt] = __builtin_amdgcn_mfma_f32_32x32x16_f16(kf1[ds], qf[mt][ds], s1[mt], 0, 0, 0);
            }
        __builtin_amdgcn_s_setprio(0);

        // ---- issue K(t+1) into kf regs (dead after QK); hides under
        //      softmax+PV (~1.5k cy >> L2 latency) ----
        if (more) {
#pragma unroll
            for (int ds = 0; ds < 4; ++ds) {
                kf0[ds] = *(const f16x8*)&KhN[offA[ds]];
                kf1[ds] = *(const f16x8*)&KhN[offA[ds] + 2048];
            }
        }

#pragma unroll
        for (int mt = 0; mt < MT; ++mt) {
            // ---- in-register softmax: pairwise fmax + max3 tree + cross-half ----
            float t[16];
#pragma unroll
            for (int r = 0; r < 16; ++r) t[r] = fmaxf(s0[mt][r], s1[mt][r]);
            const float u0 = max3f(t[0],  t[1],  t[2]);
            const float u1 = max3f(t[3],  t[4],  t[5]);
            const float u2 = max3f(t[6],  t[7],  t[8]);
            const float u3 = max3f(t[9],  t[10], t[11]);
            const float u4 = max3f(t[12], t[13], t[14]);
            float rm = fmaxf(max3f(u0, u1, u2), max3f(u3, u4, t[15]));
            rm = xhalf_max(rm);

            if (!__all(rm <= m_i[mt] + kDeferThr)) {
                const float mnew  = fmaxf(m_i[mt], rm);
                const float alpha = __builtin_amdgcn_exp2f(m_i[mt] - mnew);
                ol[mt][0] *= alpha;
#pragma unroll
                for (int r = 0; r < 16; ++r) { oL[mt][r] *= alpha; oH[mt][r] *= alpha; }
                m_i[mt] = mnew;
            }

#pragma unroll
            for (int r = 0; r < 16; ++r) {
                s0[mt][r] = __builtin_amdgcn_exp2f(s0[mt][r] - m_i[mt]);
                s1[mt][r] = __builtin_amdgcn_exp2f(s1[mt][r] - m_i[mt]);
            }

            // ---- P -> fp16 fragments ----
            f16x8 pa[4];
            PA_SLICE(pa[0], s0[mt], 0);
            PA_SLICE(pa[1], s0[mt], 8);
            PA_SLICE(pa[2], s1[mt], 0);
            PA_SLICE(pa[3], s1[mt], 8);

            // ---- PV + fused l (compiler waits vf's vmcnt) ----
            __builtin_amdgcn_s_setprio(1);
#pragma unroll
            for (int s = 0; s < 4; ++s) {
                oL[mt] = __builtin_amdgcn_mfma_f32_32x32x16_f16(vf0[s], pa[s], oL[mt], 0, 0, 0);
                oH[mt] = __builtin_amdgcn_mfma_f32_32x32x16_f16(vf1[s], pa[s], oH[mt], 0, 0, 0);
                ol[mt] = __builtin_amdgcn_mfma_f32_32x32x16_f16(ones,   pa[s], ol[mt], 0, 0, 0);
            }
            __builtin_amdgcn_s_setprio(0);
        }

        // ---- issue V(t+1) into vf regs (dead after PV); hides under next
        //      QK+softmax ----
        if (more) {
#pragma unroll
            for (int s = 0; s < 4; ++s) {
                vf0[s] = *(const f16x8*)&VtN[offA[s]];
                vf1[s] = *(const f16x8*)&VtN[offA[s] + 2048];
            }
        }
    }

    // ---- epilogue 1: normalized partials -> LDS ----
#pragma unroll
    for (int mt = 0; mt < MT; ++mt) {
        const int ql = mt * 32 + l31;            // 0..63
        const float lf = ol[mt][0];
        const float inv = 1.0f / lf;
        _Float16* prow = &sPart[mh * 4 + ks][ql][0];
#pragma unroll
        for (int g = 0; g < 4; ++g) {
            *(f16x4*)&prow[g * 8 + hi * 4] =
                pack4(oL[mt][4 * g] * inv, oL[mt][4 * g + 1] * inv,
                      oL[mt][4 * g + 2] * inv, oL[mt][4 * g + 3] * inv);
            *(f16x4*)&prow[32 + g * 8 + hi * 4] =
                pack4(oH[mt][4 * g] * inv, oH[mt][4 * g + 1] * inv,
                      oH[mt][4 * g + 2] * inv, oH[mt][4 * g + 3] * inv);
        }
        if (hi == 0) sMl[mh * 4 + ks][ql] = make_float2(m_i[mt], lf);
    }
    __syncthreads();   // the ONLY barrier in the kernel

    // ---- epilogue 2: in-LDS combine, write O ----
    {
        const int qrow = tid >> 2;               // 0..127
        const int cc   = (tid & 3) * 16;         // 16 cols per thread
        const int emh  = qrow >> 6;
        const int eql  = qrow & 63;

        float2 ml[KSPLIT];
        float m = -1e30f;
#pragma unroll
        for (int s = 0; s < KSPLIT; ++s) {
            ml[s] = sMl[emh * 4 + s][eql];
            m = fmaxf(m, ml[s].x);
        }
        float wgt[KSPLIT];
        float lsum = 0.f;
#pragma unroll
        for (int s = 0; s < KSPLIT; ++s) {
            wgt[s] = __builtin_amdgcn_exp2f(ml[s].x - m) * ml[s].y;
            lsum += wgt[s];
        }
        const float inv = 1.0f / lsum;

        float* orow = Og + (((size_t)b * kSQ + qb + qrow)) * kD + cc;
#pragma unroll
        for (int j = 0; j < 4; ++j) {
            float a0 = 0.f, a1 = 0.f, a2 = 0.f, a3 = 0.f;
#pragma unroll
            for (int s = 0; s < KSPLIT; ++s) {
                const f16x4 a = *(const f16x4*)&sPart[emh * 4 + s][eql][cc + j * 4];
                a0 += wgt[s] * (float)a[0];
                a1 += wgt[s] * (float)a[1];
                a2 += wgt[s] * (float)a[2];
                a3 += wgt[s] * (float)a[3];
            }
            *(float4*)&orow[j * 4] = make_float4(a0 * inv, a1 * inv, a2 * inv, a3 * inv);
        }
    }
}

extern "C" void kernel_launch(void* const* d_in, const int* in_sizes, int n_in,
                              void* d_out, int out_size, void* d_ws, size_t ws_size,
                              hipStream_t stream) {
    const float* Q    = (const float*)d_in[0];
    const float* K    = (const float*)d_in[1];
    const float* V    = (const float*)d_in[2];
    const float* sdiv = (const float*)d_in[4];
    float* O = (float*)d_out;

    // workspace: Kh 4MB | Vt 4MB
    _Float16* Kh  = (_Float16*)d_ws;
    _Float16* Vt  = Kh + (size_t)kB * kSK * kD;

    fattn_prepass<<<dim3(kSK / BK, kB), dim3(256), 0, stream>>>(K, V, Kh, Vt);
    fattn_fused<<<dim3(kB * (kSQ / BQ)), dim3(512), 0, stream>>>(Q, Kh, Vt, sdiv, O);
}